// Round 6
// baseline (180.903 us; speedup 1.0000x reference)
//
#include <hip/hip_runtime.h>
#include <hip/hip_bf16.h>
#include <stdint.h>

#define B_ 4
#define S_ 2048
#define D_ 512
#define H_ 8
#define HD_ 64
#define M_ (B_*S_)   // 8192

typedef __bf16 bf16x8 __attribute__((ext_vector_type(8)));
typedef float f32x4 __attribute__((ext_vector_type(4)));

__device__ __forceinline__ unsigned short f2b(float f) {
  union { float f; unsigned u; } v; v.f = f;
  unsigned r = v.u + 0x7fff + ((v.u >> 16) & 1);
  return (unsigned short)(r >> 16);
}

__device__ __forceinline__ unsigned short f2b_fast(float f) {  // round-half-up, for P>=0
  union { float f; unsigned u; } v; v.f = f;
  return (unsigned short)((v.u + 0x8000u) >> 16);
}

__device__ __forceinline__ float exp2_hw(float x) {
  return __builtin_amdgcn_exp2f(x);  // v_exp_f32: D = 2^S0
}

__device__ __forceinline__ void gload16(const void* g, void* lds) {
  __builtin_amdgcn_global_load_lds(
      (const __attribute__((address_space(1))) unsigned int*)g,
      (__attribute__((address_space(3))) unsigned int*)lds, 16, 0, 0);
}

// ---------------- f32 -> bf16 conversion (x + all 4 weights, one launch) ----------------
#define XN4 (M_ * D_ / 4)        // 1048576 float4's of x
#define WN4 (D_ * D_ / 4)        // 65536 float4's per weight
__global__ __launch_bounds__(256) void cvt_all_kernel(const float* __restrict__ x,
    const float* __restrict__ wq, const float* __restrict__ wk,
    const float* __restrict__ wv, const float* __restrict__ wo,
    unsigned short* __restrict__ xb, unsigned short* __restrict__ wqb,
    unsigned short* __restrict__ wkb, unsigned short* __restrict__ wvb,
    unsigned short* __restrict__ wob) {
  int i = blockIdx.x * blockDim.x + threadIdx.x;
  const float* src; unsigned short* dst; int off;
  if (i < XN4) { src = x; dst = xb; off = i; }
  else {
    int j = i - XN4;
    int sel = j / WN4; off = j - sel * WN4;
    src = (sel == 0) ? wq : (sel == 1) ? wk : (sel == 2) ? wv : wo;
    dst = (sel == 0) ? wqb : (sel == 1) ? wkb : (sel == 2) ? wvb : wob;
  }
  float4 v = ((const float4*)src)[off];
  ushort4 o;
  o.x = f2b(v.x); o.y = f2b(v.y); o.z = f2b(v.z); o.w = f2b(v.w);
  ((ushort4*)dst)[off] = o;
}

// ---------------- GEMM core: C[128x128] = A[128xK] * B^T (B is [N][K]) ----------------
__device__ __forceinline__ void gemm_core(const unsigned short* __restrict__ A,
                                          const unsigned short* __restrict__ W,
                                          int m0, int n0, f32x4 (&acc)[4][4],
                                          unsigned short* As, unsigned short* Bs) {
  int tid = threadIdx.x;
  int w = tid >> 6, lane = tid & 63;
  int l15 = lane & 15, g = lane >> 4;
  int wr = w >> 1, wc = w & 1;
  for (int k0 = 0; k0 < D_; k0 += 64) {
    #pragma unroll
    for (int i = 0; i < 4; ++i) {
      int l = i * 256 + w * 64 + lane;
      int row = l >> 3, seg = l & 7;
      int sseg = seg ^ (row & 7);
      gload16(A + (size_t)(m0 + row) * D_ + k0 + sseg * 8,
              (char*)As + (size_t)(i * 256 + w * 64) * 16);
      gload16(W + (size_t)(n0 + row) * D_ + k0 + sseg * 8,
              (char*)Bs + (size_t)(i * 256 + w * 64) * 16);
    }
    __syncthreads();
    #pragma unroll
    for (int kk = 0; kk < 2; ++kk) {
      int sw = ((kk * 4 + g) ^ (l15 & 7)) * 8;
      bf16x8 af[4], bfr[4];
      #pragma unroll
      for (int t = 0; t < 4; ++t) {
        af[t]  = *(const bf16x8*)&As[(wr * 64 + t * 16 + l15) * 64 + sw];
        bfr[t] = *(const bf16x8*)&Bs[(wc * 64 + t * 16 + l15) * 64 + sw];
      }
      #pragma unroll
      for (int mi = 0; mi < 4; ++mi)
        #pragma unroll
        for (int ni = 0; ni < 4; ++ni)
          acc[mi][ni] = __builtin_amdgcn_mfma_f32_16x16x32_bf16(af[mi], bfr[ni], acc[mi][ni], 0, 0, 0);
    }
    __syncthreads();
  }
}

// ---------------- QKV projection ----------------
__global__ __launch_bounds__(256) void gemm_qkv(const unsigned short* __restrict__ xb,
    const unsigned short* __restrict__ wqb, const unsigned short* __restrict__ wkb,
    const unsigned short* __restrict__ wvb,
    const float* __restrict__ bq, const float* __restrict__ bk, const float* __restrict__ bv,
    unsigned short* __restrict__ Qb, unsigned short* __restrict__ Kb, unsigned short* __restrict__ Vtb) {
  __shared__ unsigned short As[128 * 64], Bs[128 * 64];
  int z = blockIdx.z;
  const unsigned short* W = (z == 0) ? wqb : ((z == 1) ? wkb : wvb);
  const float* bias = (z == 0) ? bq : ((z == 1) ? bk : bv);
  int m0 = blockIdx.x * 128, n0 = blockIdx.y * 128;
  f32x4 zero4 = {0.f, 0.f, 0.f, 0.f};
  f32x4 acc[4][4];
  #pragma unroll
  for (int mi = 0; mi < 4; ++mi)
    #pragma unroll
    for (int ni = 0; ni < 4; ++ni) acc[mi][ni] = zero4;
  gemm_core(xb, W, m0, n0, acc, As, Bs);
  int tid = threadIdx.x;
  int w = tid >> 6, lane = tid & 63, l15 = lane & 15, g = lane >> 4;
  int wr = w >> 1, wc = w & 1;
  #pragma unroll
  for (int mi = 0; mi < 4; ++mi)
    #pragma unroll
    for (int ni = 0; ni < 4; ++ni) {
      int e = n0 + wc * 64 + ni * 16 + l15;
      float bb = bias[e];
      int h = e >> 6, dd = e & 63;
      #pragma unroll
      for (int r = 0; r < 4; ++r) {
        int m = m0 + wr * 64 + mi * 16 + g * 4 + r;
        int b = m >> 11, s = m & 2047;
        unsigned short u = f2b(acc[mi][ni][r] + bb);
        int bh = b * H_ + h;
        if (z == 0)      Qb[((size_t)bh * S_ + s) * HD_ + dd] = u;
        else if (z == 1) Kb[((size_t)bh * S_ + s) * HD_ + dd] = u;
        else             Vtb[((size_t)bh * HD_ + dd) * S_ + s] = u;  // V transposed
      }
    }
}

// ---------------- output projection -> f32 tmp ----------------
__global__ __launch_bounds__(256) void gemm_proj(const unsigned short* __restrict__ AOb,
    const unsigned short* __restrict__ wob, const float* __restrict__ bo, float* __restrict__ Pf) {
  __shared__ unsigned short As[128 * 64], Bs[128 * 64];
  int m0 = blockIdx.x * 128, n0 = blockIdx.y * 128;
  f32x4 zero4 = {0.f, 0.f, 0.f, 0.f};
  f32x4 acc[4][4];
  #pragma unroll
  for (int mi = 0; mi < 4; ++mi)
    #pragma unroll
    for (int ni = 0; ni < 4; ++ni) acc[mi][ni] = zero4;
  gemm_core(AOb, wob, m0, n0, acc, As, Bs);
  int tid = threadIdx.x;
  int w = tid >> 6, lane = tid & 63, l15 = lane & 15, g = lane >> 4;
  int wr = w >> 1, wc = w & 1;
  #pragma unroll
  for (int mi = 0; mi < 4; ++mi)
    #pragma unroll
    for (int ni = 0; ni < 4; ++ni) {
      int e = n0 + wc * 64 + ni * 16 + l15;
      float bb = bo[e];
      #pragma unroll
      for (int r = 0; r < 4; ++r) {
        int m = m0 + wr * 64 + mi * 16 + g * 4 + r;
        Pf[(size_t)m * D_ + e] = acc[mi][ni][r] + bb;
      }
    }
}

// ---------------- flash attention (2-phase dbuf, QBLK=64, 4 waves x 16 rows) ----------------
__global__ __launch_bounds__(256) void attn_kernel(const unsigned short* __restrict__ Qb,
    const unsigned short* __restrict__ Kb, const unsigned short* __restrict__ Vtb,
    const int* __restrict__ mask, const float* __restrict__ tptr,
    unsigned short* __restrict__ AOb) {
  __shared__ unsigned short Ks[2][64 * 64], Vs[2][64 * 64];
  __shared__ unsigned short Pw[4][16 * 64];
  int bh = blockIdx.y, b = bh >> 3, h = bh & 7;
  int tid = threadIdx.x, w = tid >> 6, lane = tid & 63, l15 = lane & 15, g = lane >> 4;
  float tl2 = tptr[0] * 1.44269504088896340736f;  // temp * log2(e)
  int q0 = blockIdx.x * 64 + w * 16;
  const unsigned short* Qbase = Qb + (size_t)bh * S_ * HD_;
  const int* mbase = mask + (size_t)b * S_;
  bf16x8 qf[2];
  #pragma unroll
  for (int kk = 0; kk < 2; ++kk)
    qf[kk] = *(const bf16x8*)&Qbase[(size_t)(q0 + l15) * HD_ + kk * 32 + g * 8];
  bf16x8 ones;
  #pragma unroll
  for (int j = 0; j < 8; ++j) ones[j] = (__bf16)1.0f;

  f32x4 zero4 = {0.f, 0.f, 0.f, 0.f};
  f32x4 of[5];              // [4] = row-sum accumulator (ones column)
  float mr[4];
  #pragma unroll
  for (int dj = 0; dj < 5; ++dj) of[dj] = zero4;
  #pragma unroll
  for (int r = 0; r < 4; ++r) mr[r] = -INFINITY;

  // stage tile into buffer buf
  #define STAGE_KV(buf, kb_) do {                                              \
    _Pragma("unroll")                                                          \
    for (int i = 0; i < 2; ++i) {                                              \
      int l = i * 256 + w * 64 + lane;                                         \
      int row = l >> 3, seg = l & 7;                                           \
      int sseg = seg ^ (row & 7);                                              \
      gload16(Kb + ((size_t)bh * S_ + (kb_) + row) * HD_ + sseg * 8,           \
              (char*)Ks[buf] + (size_t)(i * 256 + w * 64) * 16);               \
      gload16(Vtb + ((size_t)bh * HD_ + row) * S_ + (kb_) + sseg * 8,          \
              (char*)Vs[buf] + (size_t)(i * 256 + w * 64) * 16);               \
    }                                                                          \
  } while (0)

  int mvn[4];
  STAGE_KV(0, 0);
  #pragma unroll
  for (int ni = 0; ni < 4; ++ni) mvn[ni] = mbase[ni * 16 + l15];
  __syncthreads();

  for (int kt = 0; kt < 32; ++kt) {
    int cur = kt & 1;
    float bv[4];
    #pragma unroll
    for (int ni = 0; ni < 4; ++ni) bv[ni] = (mvn[ni] != 0) ? -1e9f : 0.f;
    if (kt < 31) {
      STAGE_KV(cur ^ 1, (kt + 1) * 64);
      #pragma unroll
      for (int ni = 0; ni < 4; ++ni) mvn[ni] = mbase[(kt + 1) * 64 + ni * 16 + l15];
    }
    // ---- QK^T ----
    f32x4 sf[4];
    #pragma unroll
    for (int ni = 0; ni < 4; ++ni) sf[ni] = zero4;
    __builtin_amdgcn_s_setprio(1);
    #pragma unroll
    for (int kk = 0; kk < 2; ++kk) {
      int sw = ((kk * 4 + g) ^ (l15 & 7)) * 8;
      bf16x8 kf[4];
      #pragma unroll
      for (int ni = 0; ni < 4; ++ni) kf[ni] = *(const bf16x8*)&Ks[cur][(ni * 16 + l15) * 64 + sw];
      #pragma unroll
      for (int ni = 0; ni < 4; ++ni)
        sf[ni] = __builtin_amdgcn_mfma_f32_16x16x32_bf16(qf[kk], kf[ni], sf[ni], 0, 0, 0);
    }
    __builtin_amdgcn_s_setprio(0);
    // ---- scale + mask-bias (exp2 domain), per-tile max ----
    float pm[4];
    #pragma unroll
    for (int r = 0; r < 4; ++r) {
      float mx = -INFINITY;
      #pragma unroll
      for (int ni = 0; ni < 4; ++ni) {
        float v = fmaf(sf[ni][r], tl2, bv[ni]);
        sf[ni][r] = v;
        mx = fmaxf(mx, v);
      }
      pm[r] = mx;
    }
    #pragma unroll
    for (int r = 0; r < 4; ++r)
      #pragma unroll
      for (int d = 1; d < 16; d <<= 1) pm[r] = fmaxf(pm[r], __shfl_xor(pm[r], d));
    // ---- defer-max rescale (THR=8) ----
    float dmax = -INFINITY;
    #pragma unroll
    for (int r = 0; r < 4; ++r) dmax = fmaxf(dmax, pm[r] - mr[r]);
    if (!__all(dmax <= 8.0f)) {
      #pragma unroll
      for (int r = 0; r < 4; ++r) {
        float mn = fmaxf(mr[r], pm[r]);
        float al = exp2_hw(mr[r] - mn);
        mr[r] = mn;
        #pragma unroll
        for (int dj = 0; dj < 5; ++dj) of[dj][r] *= al;
      }
    }
    // ---- P = exp2(v - m), write to per-wave LDS (swizzled) ----
    #pragma unroll
    for (int ni = 0; ni < 4; ++ni)
      #pragma unroll
      for (int r = 0; r < 4; ++r) {
        float p = exp2_hw(sf[ni][r] - mr[r]);
        int prow = g * 4 + r;
        int pcol = (ni * 16 + l15) ^ ((prow & 7) << 3);
        Pw[w][prow * 64 + pcol] = f2b_fast(p);
      }
    // ---- PV (+ ones column -> row-sum) ----
    __builtin_amdgcn_s_setprio(1);
    #pragma unroll
    for (int kk = 0; kk < 2; ++kk) {
      int sw = ((kk * 4 + g) ^ (l15 & 7)) * 8;
      bf16x8 pa, vb[4];
      pa = *(const bf16x8*)&Pw[w][l15 * 64 + sw];
      #pragma unroll
      for (int dj = 0; dj < 4; ++dj) vb[dj] = *(const bf16x8*)&Vs[cur][(dj * 16 + l15) * 64 + sw];
      #pragma unroll
      for (int dj = 0; dj < 4; ++dj)
        of[dj] = __builtin_amdgcn_mfma_f32_16x16x32_bf16(pa, vb[dj], of[dj], 0, 0, 0);
      of[4] = __builtin_amdgcn_mfma_f32_16x16x32_bf16(pa, ones, of[4], 0, 0, 0);
    }
    __builtin_amdgcn_s_setprio(0);
    __syncthreads();
  }
  // ---- epilogue: divide by row-sum, write bf16 ----
  float inv[4];
  #pragma unroll
  for (int r = 0; r < 4; ++r) inv[r] = 1.f / of[4][r];
  #pragma unroll
  for (int dj = 0; dj < 4; ++dj)
    #pragma unroll
    for (int r = 0; r < 4; ++r) {
      int q = q0 + g * 4 + r;
      int d = dj * 16 + l15;
      AOb[((size_t)b * S_ + q) * D_ + h * HD_ + d] = f2b(of[dj][r] * inv[r]);
    }
  #undef STAGE_KV
}

// ---------------- residual + LayerNorm ----------------
__global__ __launch_bounds__(256) void ln_kernel(const float* __restrict__ Pf,
    const float* __restrict__ x, const float* __restrict__ gamma,
    const float* __restrict__ beta, float* __restrict__ out) {
  int row = blockIdx.x * 4 + (threadIdx.x >> 6);
  int lane = threadIdx.x & 63;
  const float* pr = Pf + (size_t)row * D_;
  const float* xr = x + (size_t)row * D_;
  float4 a0 = *(const float4*)(pr + lane * 4);
  float4 a1 = *(const float4*)(pr + 256 + lane * 4);
  float4 b0 = *(const float4*)(xr + lane * 4);
  float4 b1 = *(const float4*)(xr + 256 + lane * 4);
  float y[8] = {a0.x + b0.x, a0.y + b0.y, a0.z + b0.z, a0.w + b0.w,
                a1.x + b1.x, a1.y + b1.y, a1.z + b1.z, a1.w + b1.w};
  float s = 0.f, s2 = 0.f;
  #pragma unroll
  for (int i = 0; i < 8; ++i) { s += y[i]; s2 += y[i] * y[i]; }
  #pragma unroll
  for (int d = 1; d < 64; d <<= 1) { s += __shfl_xor(s, d); s2 += __shfl_xor(s2, d); }
  float mu = s * (1.f / 512.f);
  float var = s2 * (1.f / 512.f) - mu * mu;
  float inv = rsqrtf(fmaxf(var, 0.f) + 1e-6f);
  float4 g0 = *(const float4*)(gamma + lane * 4);
  float4 g1 = *(const float4*)(gamma + 256 + lane * 4);
  float4 e0 = *(const float4*)(beta + lane * 4);
  float4 e1 = *(const float4*)(beta + 256 + lane * 4);
  float* orow = out + (size_t)row * D_;
  float4 o0 = {(y[0] - mu) * inv * g0.x + e0.x, (y[1] - mu) * inv * g0.y + e0.y,
               (y[2] - mu) * inv * g0.z + e0.z, (y[3] - mu) * inv * g0.w + e0.w};
  float4 o1 = {(y[4] - mu) * inv * g1.x + e1.x, (y[5] - mu) * inv * g1.y + e1.y,
               (y[6] - mu) * inv * g1.z + e1.z, (y[7] - mu) * inv * g1.w + e1.w};
  *(float4*)(orow + lane * 4) = o0;
  *(float4*)(orow + 256 + lane * 4) = o1;
}

extern "C" void kernel_launch(void* const* d_in, const int* in_sizes, int n_in,
                              void* d_out, int out_size, void* d_ws, size_t ws_size,
                              hipStream_t stream) {
  const float* x = (const float*)d_in[0];
  const int* mask = (const int*)d_in[1];
  const float* wq = (const float*)d_in[2];
  const float* bq = (const float*)d_in[3];
  const float* wk = (const float*)d_in[4];
  const float* bk = (const float*)d_in[5];
  const float* wv = (const float*)d_in[6];
  const float* bv = (const float*)d_in[7];
  const float* wo = (const float*)d_in[8];
  const float* bo = (const float*)d_in[9];
  const float* gamma = (const float*)d_in[10];
  const float* beta = (const float*)d_in[11];
  const float* temp = (const float*)d_in[12];
  float* out = (float*)d_out;
  char* ws = (char*)d_ws;
  const size_t MB = (size_t)1 << 20;
  unsigned short* xb  = (unsigned short*)(ws);                    // 8 MB
  unsigned short* wqb = (unsigned short*)(ws + 8 * MB);           // 0.5 MB
  unsigned short* wkb = (unsigned short*)(ws + 8 * MB + 512 * 1024);
  unsigned short* wvb = (unsigned short*)(ws + 9 * MB);
  unsigned short* wob = (unsigned short*)(ws + 9 * MB + 512 * 1024);
  unsigned short* Qb  = (unsigned short*)(ws + 10 * MB);          // 8 MB
  unsigned short* Kb  = (unsigned short*)(ws + 18 * MB);          // 8 MB
  float*          Pf  = (float*)(ws + 10 * MB);                   // 16 MB, overlays Q/K (used after attn)
  unsigned short* Vtb = (unsigned short*)(ws + 26 * MB);          // 8 MB
  unsigned short* AOb = (unsigned short*)(ws + 34 * MB);          // 8 MB

  cvt_all_kernel<<<(XN4 + 4 * WN4 + 255) / 256, 256, 0, stream>>>(
      x, wq, wk, wv, wo, xb, wqb, wkb, wvb, wob);
  gemm_qkv<<<dim3(64, 4, 3), 256, 0, stream>>>(xb, wqb, wkb, wvb, bq, bk, bv, Qb, Kb, Vtb);
  attn_kernel<<<dim3(32, 32), 256, 0, stream>>>(Qb, Kb, Vtb, mask, temp, AOb);
  gemm_proj<<<dim3(64, 4), 256, 0, stream>>>(AOb, wob, bo, Pf);
  ln_kernel<<<2048, 256, 0, stream>>>(Pf, x, gamma, beta, out);
}

// Round 7
// 125.513 us; speedup vs baseline: 1.4413x; 1.4413x over previous
//
#include <hip/hip_runtime.h>
#include <hip/hip_bf16.h>
#include <stdint.h>

#define B_ 4
#define S_ 2048
#define D_ 512
#define H_ 8
#define HD_ 64
#define M_ (B_*S_)   // 8192

typedef __bf16 bf16x8 __attribute__((ext_vector_type(8)));
typedef float f32x4 __attribute__((ext_vector_type(4)));

__device__ __forceinline__ unsigned short f2b(float f) {
  union { float f; unsigned u; } v; v.f = f;
  unsigned r = v.u + 0x7fff + ((v.u >> 16) & 1);
  return (unsigned short)(r >> 16);
}

__device__ __forceinline__ unsigned short f2b_fast(float f) {  // round-half-up, for P>=0
  union { float f; unsigned u; } v; v.f = f;
  return (unsigned short)((v.u + 0x8000u) >> 16);
}

__device__ __forceinline__ float exp2_hw(float x) {
  return __builtin_amdgcn_exp2f(x);  // v_exp_f32: D = 2^S0
}

__device__ __forceinline__ void gload16(const void* g, void* lds) {
  __builtin_amdgcn_global_load_lds(
      (const __attribute__((address_space(1))) unsigned int*)g,
      (__attribute__((address_space(3))) unsigned int*)lds, 16, 0, 0);
}

// ---------------- f32 -> bf16 conversion (x + all 4 weights, one launch) ----------------
#define XN4 (M_ * D_ / 4)        // 1048576 float4's of x
#define WN4 (D_ * D_ / 4)        // 65536 float4's per weight
__global__ __launch_bounds__(256) void cvt_all_kernel(const float* __restrict__ x,
    const float* __restrict__ wq, const float* __restrict__ wk,
    const float* __restrict__ wv, const float* __restrict__ wo,
    unsigned short* __restrict__ xb, unsigned short* __restrict__ wqb,
    unsigned short* __restrict__ wkb, unsigned short* __restrict__ wvb,
    unsigned short* __restrict__ wob) {
  int i = blockIdx.x * blockDim.x + threadIdx.x;
  const float* src; unsigned short* dst; int off;
  if (i < XN4) { src = x; dst = xb; off = i; }
  else {
    int j = i - XN4;
    int sel = j / WN4; off = j - sel * WN4;
    src = (sel == 0) ? wq : (sel == 1) ? wk : (sel == 2) ? wv : wo;
    dst = (sel == 0) ? wqb : (sel == 1) ? wkb : (sel == 2) ? wvb : wob;
  }
  float4 v = ((const float4*)src)[off];
  ushort4 o;
  o.x = f2b(v.x); o.y = f2b(v.y); o.z = f2b(v.z); o.w = f2b(v.w);
  ((ushort4*)dst)[off] = o;
}

// ---------------- GEMM core: C[128x128] = A[128xK] * B^T (B is [N][K]) ----------------
__device__ __forceinline__ void gemm_core(const unsigned short* __restrict__ A,
                                          const unsigned short* __restrict__ W,
                                          int m0, int n0, f32x4 (&acc)[4][4],
                                          unsigned short* As, unsigned short* Bs) {
  int tid = threadIdx.x;
  int w = tid >> 6, lane = tid & 63;
  int l15 = lane & 15, g = lane >> 4;
  int wr = w >> 1, wc = w & 1;
  for (int k0 = 0; k0 < D_; k0 += 64) {
    #pragma unroll
    for (int i = 0; i < 4; ++i) {
      int l = i * 256 + w * 64 + lane;
      int row = l >> 3, seg = l & 7;
      int sseg = seg ^ (row & 7);
      gload16(A + (size_t)(m0 + row) * D_ + k0 + sseg * 8,
              (char*)As + (size_t)(i * 256 + w * 64) * 16);
      gload16(W + (size_t)(n0 + row) * D_ + k0 + sseg * 8,
              (char*)Bs + (size_t)(i * 256 + w * 64) * 16);
    }
    __syncthreads();
    #pragma unroll
    for (int kk = 0; kk < 2; ++kk) {
      int sw = ((kk * 4 + g) ^ (l15 & 7)) * 8;
      bf16x8 af[4], bfr[4];
      #pragma unroll
      for (int t = 0; t < 4; ++t) {
        af[t]  = *(const bf16x8*)&As[(wr * 64 + t * 16 + l15) * 64 + sw];
        bfr[t] = *(const bf16x8*)&Bs[(wc * 64 + t * 16 + l15) * 64 + sw];
      }
      #pragma unroll
      for (int mi = 0; mi < 4; ++mi)
        #pragma unroll
        for (int ni = 0; ni < 4; ++ni)
          acc[mi][ni] = __builtin_amdgcn_mfma_f32_16x16x32_bf16(af[mi], bfr[ni], acc[mi][ni], 0, 0, 0);
    }
    __syncthreads();
  }
}

// ---------------- QKV projection ----------------
__global__ __launch_bounds__(256) void gemm_qkv(const unsigned short* __restrict__ xb,
    const unsigned short* __restrict__ wqb, const unsigned short* __restrict__ wkb,
    const unsigned short* __restrict__ wvb,
    const float* __restrict__ bq, const float* __restrict__ bk, const float* __restrict__ bv,
    unsigned short* __restrict__ Qb, unsigned short* __restrict__ Kb, unsigned short* __restrict__ Vtb) {
  __shared__ unsigned short As[128 * 64], Bs[128 * 64];
  int z = blockIdx.z;
  const unsigned short* W = (z == 0) ? wqb : ((z == 1) ? wkb : wvb);
  const float* bias = (z == 0) ? bq : ((z == 1) ? bk : bv);
  int m0 = blockIdx.x * 128, n0 = blockIdx.y * 128;
  f32x4 zero4 = {0.f, 0.f, 0.f, 0.f};
  f32x4 acc[4][4];
  #pragma unroll
  for (int mi = 0; mi < 4; ++mi)
    #pragma unroll
    for (int ni = 0; ni < 4; ++ni) acc[mi][ni] = zero4;
  gemm_core(xb, W, m0, n0, acc, As, Bs);
  int tid = threadIdx.x;
  int w = tid >> 6, lane = tid & 63, l15 = lane & 15, g = lane >> 4;
  int wr = w >> 1, wc = w & 1;
  #pragma unroll
  for (int mi = 0; mi < 4; ++mi)
    #pragma unroll
    for (int ni = 0; ni < 4; ++ni) {
      int e = n0 + wc * 64 + ni * 16 + l15;
      float bb = bias[e];
      int h = e >> 6, dd = e & 63;
      #pragma unroll
      for (int r = 0; r < 4; ++r) {
        int m = m0 + wr * 64 + mi * 16 + g * 4 + r;
        int b = m >> 11, s = m & 2047;
        unsigned short u = f2b(acc[mi][ni][r] + bb);
        int bh = b * H_ + h;
        if (z == 0)      Qb[((size_t)bh * S_ + s) * HD_ + dd] = u;
        else if (z == 1) Kb[((size_t)bh * S_ + s) * HD_ + dd] = u;
        else             Vtb[((size_t)bh * HD_ + dd) * S_ + s] = u;  // V transposed
      }
    }
}

// ---------------- output projection -> f32 tmp ----------------
__global__ __launch_bounds__(256) void gemm_proj(const unsigned short* __restrict__ AOb,
    const unsigned short* __restrict__ wob, const float* __restrict__ bo, float* __restrict__ Pf) {
  __shared__ unsigned short As[128 * 64], Bs[128 * 64];
  int m0 = blockIdx.x * 128, n0 = blockIdx.y * 128;
  f32x4 zero4 = {0.f, 0.f, 0.f, 0.f};
  f32x4 acc[4][4];
  #pragma unroll
  for (int mi = 0; mi < 4; ++mi)
    #pragma unroll
    for (int ni = 0; ni < 4; ++ni) acc[mi][ni] = zero4;
  gemm_core(AOb, wob, m0, n0, acc, As, Bs);
  int tid = threadIdx.x;
  int w = tid >> 6, lane = tid & 63, l15 = lane & 15, g = lane >> 4;
  int wr = w >> 1, wc = w & 1;
  #pragma unroll
  for (int mi = 0; mi < 4; ++mi)
    #pragma unroll
    for (int ni = 0; ni < 4; ++ni) {
      int e = n0 + wc * 64 + ni * 16 + l15;
      float bb = bo[e];
      #pragma unroll
      for (int r = 0; r < 4; ++r) {
        int m = m0 + wr * 64 + mi * 16 + g * 4 + r;
        Pf[(size_t)m * D_ + e] = acc[mi][ni][r] + bb;
      }
    }
}

// ---------------- flash attention (QBLK=128, 2-phase dbuf, static-max softmax) ----------------
__global__ __launch_bounds__(256) void attn_kernel(const unsigned short* __restrict__ Qb,
    const unsigned short* __restrict__ Kb, const unsigned short* __restrict__ Vtb,
    const int* __restrict__ mask, const float* __restrict__ tptr,
    unsigned short* __restrict__ AOb) {
  __shared__ unsigned short Ks[2][64 * 64], Vs[2][64 * 64];
  __shared__ unsigned short Pw[4][32 * 64];
  int bh = blockIdx.y, b = bh >> 3, h = bh & 7;
  int tid = threadIdx.x, w = tid >> 6, lane = tid & 63, l15 = lane & 15, g = lane >> 4;
  float tl2 = tptr[0] * 1.44269504088896340736f;  // temp * log2(e)
  int q0 = blockIdx.x * 128 + w * 32;
  const unsigned short* Qbase = Qb + (size_t)bh * S_ * HD_;
  const int* mbase = mask + (size_t)b * S_;
  bf16x8 qf[2][2];
  #pragma unroll
  for (int mi = 0; mi < 2; ++mi)
    #pragma unroll
    for (int kk = 0; kk < 2; ++kk)
      qf[mi][kk] = *(const bf16x8*)&Qbase[(size_t)(q0 + mi * 16 + l15) * HD_ + kk * 32 + g * 8];
  bf16x8 ones;
  #pragma unroll
  for (int j = 0; j < 8; ++j) ones[j] = (__bf16)1.0f;

  f32x4 zero4 = {0.f, 0.f, 0.f, 0.f};
  f32x4 of[2][5];           // [..][4] = row-sum accumulator (ones column)
  #pragma unroll
  for (int mi = 0; mi < 2; ++mi)
    #pragma unroll
    for (int dj = 0; dj < 5; ++dj) of[mi][dj] = zero4;

  // stage tile into buffer buf
  #define STAGE_KV(buf, kb_) do {                                              \
    _Pragma("unroll")                                                          \
    for (int i = 0; i < 2; ++i) {                                              \
      int l = i * 256 + w * 64 + lane;                                         \
      int row = l >> 3, seg = l & 7;                                           \
      int sseg = seg ^ (row & 7);                                              \
      gload16(Kb + ((size_t)bh * S_ + (kb_) + row) * HD_ + sseg * 8,           \
              (char*)Ks[buf] + (size_t)(i * 256 + w * 64) * 16);               \
      gload16(Vtb + ((size_t)bh * HD_ + row) * S_ + (kb_) + sseg * 8,          \
              (char*)Vs[buf] + (size_t)(i * 256 + w * 64) * 16);               \
    }                                                                          \
  } while (0)

  int mvn[4];
  STAGE_KV(0, 0);
  #pragma unroll
  for (int ni = 0; ni < 4; ++ni) mvn[ni] = mbase[ni * 16 + l15];
  __syncthreads();

  for (int kt = 0; kt < 32; ++kt) {
    int cur = kt & 1;
    float bv[4];
    #pragma unroll
    for (int ni = 0; ni < 4; ++ni) bv[ni] = (mvn[ni] != 0) ? -1e9f : 0.f;
    if (kt < 31) {
      STAGE_KV(cur ^ 1, (kt + 1) * 64);
      #pragma unroll
      for (int ni = 0; ni < 4; ++ni) mvn[ni] = mbase[(kt + 1) * 64 + ni * 16 + l15];
    }
    // ---- QK^T ----
    f32x4 sf[2][4];
    #pragma unroll
    for (int mi = 0; mi < 2; ++mi)
      #pragma unroll
      for (int ni = 0; ni < 4; ++ni) sf[mi][ni] = zero4;
    __builtin_amdgcn_s_setprio(1);
    #pragma unroll
    for (int kk = 0; kk < 2; ++kk) {
      int sw = ((kk * 4 + g) ^ (l15 & 7)) * 8;
      bf16x8 kf[4];
      #pragma unroll
      for (int ni = 0; ni < 4; ++ni) kf[ni] = *(const bf16x8*)&Ks[cur][(ni * 16 + l15) * 64 + sw];
      #pragma unroll
      for (int mi = 0; mi < 2; ++mi)
        #pragma unroll
        for (int ni = 0; ni < 4; ++ni)
          sf[mi][ni] = __builtin_amdgcn_mfma_f32_16x16x32_bf16(qf[mi][kk], kf[ni], sf[mi][ni], 0, 0, 0);
    }
    __builtin_amdgcn_s_setprio(0);
    // ---- P = exp2(s*tl2 + bias) (static max = 0), write to per-wave LDS (swizzled) ----
    #pragma unroll
    for (int mi = 0; mi < 2; ++mi)
      #pragma unroll
      for (int ni = 0; ni < 4; ++ni)
        #pragma unroll
        for (int r = 0; r < 4; ++r) {
          float p = exp2_hw(fmaf(sf[mi][ni][r], tl2, bv[ni]));
          int prow = mi * 16 + g * 4 + r;
          int pcol = (ni * 16 + l15) ^ ((prow & 7) << 3);
          Pw[w][prow * 64 + pcol] = f2b_fast(p);
        }
    // ---- PV (+ ones column -> row-sum) ----
    __builtin_amdgcn_s_setprio(1);
    #pragma unroll
    for (int kk = 0; kk < 2; ++kk) {
      int sw = ((kk * 4 + g) ^ (l15 & 7)) * 8;
      bf16x8 pa[2], vb[4];
      #pragma unroll
      for (int mi = 0; mi < 2; ++mi) pa[mi] = *(const bf16x8*)&Pw[w][(mi * 16 + l15) * 64 + sw];
      #pragma unroll
      for (int dj = 0; dj < 4; ++dj) vb[dj] = *(const bf16x8*)&Vs[cur][(dj * 16 + l15) * 64 + sw];
      #pragma unroll
      for (int mi = 0; mi < 2; ++mi) {
        #pragma unroll
        for (int dj = 0; dj < 4; ++dj)
          of[mi][dj] = __builtin_amdgcn_mfma_f32_16x16x32_bf16(pa[mi], vb[dj], of[mi][dj], 0, 0, 0);
        of[mi][4] = __builtin_amdgcn_mfma_f32_16x16x32_bf16(pa[mi], ones, of[mi][4], 0, 0, 0);
      }
    }
    __builtin_amdgcn_s_setprio(0);
    __syncthreads();
  }
  // ---- epilogue: divide by row-sum, write bf16 ----
  #pragma unroll
  for (int mi = 0; mi < 2; ++mi) {
    float inv[4];
    #pragma unroll
    for (int r = 0; r < 4; ++r) inv[r] = 1.f / of[mi][4][r];
    #pragma unroll
    for (int dj = 0; dj < 4; ++dj)
      #pragma unroll
      for (int r = 0; r < 4; ++r) {
        int q = q0 + mi * 16 + g * 4 + r;
        int d = dj * 16 + l15;
        AOb[((size_t)b * S_ + q) * D_ + h * HD_ + d] = f2b(of[mi][dj][r] * inv[r]);
      }
  }
  #undef STAGE_KV
}

// ---------------- residual + LayerNorm ----------------
__global__ __launch_bounds__(256) void ln_kernel(const float* __restrict__ Pf,
    const float* __restrict__ x, const float* __restrict__ gamma,
    const float* __restrict__ beta, float* __restrict__ out) {
  int row = blockIdx.x * 4 + (threadIdx.x >> 6);
  int lane = threadIdx.x & 63;
  const float* pr = Pf + (size_t)row * D_;
  const float* xr = x + (size_t)row * D_;
  float4 a0 = *(const float4*)(pr + lane * 4);
  float4 a1 = *(const float4*)(pr + 256 + lane * 4);
  float4 b0 = *(const float4*)(xr + lane * 4);
  float4 b1 = *(const float4*)(xr + 256 + lane * 4);
  float y[8] = {a0.x + b0.x, a0.y + b0.y, a0.z + b0.z, a0.w + b0.w,
                a1.x + b1.x, a1.y + b1.y, a1.z + b1.z, a1.w + b1.w};
  float s = 0.f, s2 = 0.f;
  #pragma unroll
  for (int i = 0; i < 8; ++i) { s += y[i]; s2 += y[i] * y[i]; }
  #pragma unroll
  for (int d = 1; d < 64; d <<= 1) { s += __shfl_xor(s, d); s2 += __shfl_xor(s2, d); }
  float mu = s * (1.f / 512.f);
  float var = s2 * (1.f / 512.f) - mu * mu;
  float inv = rsqrtf(fmaxf(var, 0.f) + 1e-6f);
  float4 g0 = *(const float4*)(gamma + lane * 4);
  float4 g1 = *(const float4*)(gamma + 256 + lane * 4);
  float4 e0 = *(const float4*)(beta + lane * 4);
  float4 e1 = *(const float4*)(beta + 256 + lane * 4);
  float* orow = out + (size_t)row * D_;
  float4 o0 = {(y[0] - mu) * inv * g0.x + e0.x, (y[1] - mu) * inv * g0.y + e0.y,
               (y[2] - mu) * inv * g0.z + e0.z, (y[3] - mu) * inv * g0.w + e0.w};
  float4 o1 = {(y[4] - mu) * inv * g1.x + e1.x, (y[5] - mu) * inv * g1.y + e1.y,
               (y[6] - mu) * inv * g1.z + e1.z, (y[7] - mu) * inv * g1.w + e1.w};
  *(float4*)(orow + lane * 4) = o0;
  *(float4*)(orow + 256 + lane * 4) = o1;
}

extern "C" void kernel_launch(void* const* d_in, const int* in_sizes, int n_in,
                              void* d_out, int out_size, void* d_ws, size_t ws_size,
                              hipStream_t stream) {
  const float* x = (const float*)d_in[0];
  const int* mask = (const int*)d_in[1];
  const float* wq = (const float*)d_in[2];
  const float* bq = (const float*)d_in[3];
  const float* wk = (const float*)d_in[4];
  const float* bk = (const float*)d_in[5];
  const float* wv = (const float*)d_in[6];
  const float* bv = (const float*)d_in[7];
  const float* wo = (const float*)d_in[8];
  const float* bo = (const float*)d_in[9];
  const float* gamma = (const float*)d_in[10];
  const float* beta = (const float*)d_in[11];
  const float* temp = (const float*)d_in[12];
  float* out = (float*)d_out;
  char* ws = (char*)d_ws;
  const size_t MB = (size_t)1 << 20;
  unsigned short* xb  = (unsigned short*)(ws);                    // 8 MB
  unsigned short* wqb = (unsigned short*)(ws + 8 * MB);           // 0.5 MB
  unsigned short* wkb = (unsigned short*)(ws + 8 * MB + 512 * 1024);
  unsigned short* wvb = (unsigned short*)(ws + 9 * MB);
  unsigned short* wob = (unsigned short*)(ws + 9 * MB + 512 * 1024);
  unsigned short* Qb  = (unsigned short*)(ws + 10 * MB);          // 8 MB
  unsigned short* Kb  = (unsigned short*)(ws + 18 * MB);          // 8 MB
  float*          Pf  = (float*)(ws + 10 * MB);                   // 16 MB, overlays Q/K (used after attn)
  unsigned short* Vtb = (unsigned short*)(ws + 26 * MB);          // 8 MB
  unsigned short* AOb = (unsigned short*)(ws + 34 * MB);          // 8 MB

  cvt_all_kernel<<<(XN4 + 4 * WN4 + 255) / 256, 256, 0, stream>>>(
      x, wq, wk, wv, wo, xb, wqb, wkb, wvb, wob);
  gemm_qkv<<<dim3(64, 4, 3), 256, 0, stream>>>(xb, wqb, wkb, wvb, bq, bk, bv, Qb, Kb, Vtb);
  attn_kernel<<<dim3(16, 32), 256, 0, stream>>>(Qb, Kb, Vtb, mask, temp, AOb);
  gemm_proj<<<dim3(64, 4), 256, 0, stream>>>(AOb, wob, bo, Pf);
  ln_kernel<<<2048, 256, 0, stream>>>(Pf, x, gamma, beta, out);
}